// Round 3
// baseline (715.240 us; speedup 1.0000x reference)
//
#include <hip/hip_runtime.h>

#define N_NODES 50000
#define N_EDGES 800000
#define D 64          // D_IN == D_OUT
#define ED 32         // EDGE_DIM
#define BN_EPS 1e-5f

// ---- workspace layout (32-bit word indices) -------------------------------
#define WS_SUMS     0
#define WS_SUMSQ    64
#define WS_PART     128                       // 64 ints: scan partials
#define WS_DEG      256
#define WS_AGGEA    (WS_DEG + N_NODES)        // 50256  (byte 201024, 16B ok)
#define WS_ZERO_END (WS_AGGEA + N_NODES * ED) // memset [0, here)  (~6.6 MB)
#define WS_OFF      WS_ZERO_END               // 1650256 (byte 6601024, 16B ok)
#define WS_CURSOR   (WS_OFF + N_NODES + 4)    // 1700260 (byte 6801040, 16B ok)
#define WS_SRC      (WS_CURSOR + N_NODES)     // 1750260
#define WS_PRE      (WS_SRC + N_EDGES)        // 2550260
#define WS_H        (WS_PRE + N_NODES * D)    // 5750260
// total = WS_H + N_NODES*D = 8950260 words ~ 35.8 MB (prev session proved >=68 MB)

#define SCAN_BLOCKS 50   // 50 x 1000 = N_NODES exactly

// ---------------------------------------------------------------------------
// Streaming pass over edge_attr: aggEA[dst] += ea[e] (f32 device atomics,
// fire-and-forget) + degree histogram. Replaces count_kernel AND the whole
// bf16 eab permute (51.2 MB random write + 51.2 MB re-read eliminated).
__global__ __launch_bounds__(256) void edge_ea_kernel(
    const int* __restrict__ dst, const float* __restrict__ ea,
    float* __restrict__ aggEA, int* __restrict__ deg)
{
    int t = blockIdx.x * 256 + threadIdx.x;
    const int stride = gridDim.x * 256;
    for (; t < N_EDGES * 8; t += stride) {      // 8 threads per edge (4 dims each)
        const int e = t >> 3;
        const int c = (t & 7) << 2;
        const int d = dst[e];
        const float4 v = ((const float4*)ea)[t];
        float* p = aggEA + (size_t)d * ED + c;
        unsafeAtomicAdd(p + 0, v.x);
        unsafeAtomicAdd(p + 1, v.y);
        unsafeAtomicAdd(p + 2, v.z);
        unsafeAtomicAdd(p + 3, v.w);
        if ((t & 7) == 0) atomicAdd(&deg[d], 1);
    }
}

// per-block partial sums over 1000 ints (coalesced int4)
__global__ __launch_bounds__(256) void scan_partial_kernel(
    const int* __restrict__ deg, int* __restrict__ partial)
{
    __shared__ int sR[256];
    const int t = threadIdx.x;
    const int base = blockIdx.x * 1000;
    int local = 0;
    if (t < 250) {
        int4 d = ((const int4*)(deg + base))[t];
        local = d.x + d.y + d.z + d.w;
    }
    sR[t] = local;
    __syncthreads();
    for (int o = 128; o > 0; o >>= 1) {
        if (t < o) sR[t] += sR[t + o];
        __syncthreads();
    }
    if (t == 0) partial[blockIdx.x] = sR[0];
}

// block-local scan + in-kernel top scan of the 50 partials; writes off & cursor
__global__ __launch_bounds__(256) void scan_write_kernel(
    const int* __restrict__ deg, const int* __restrict__ partial,
    int* __restrict__ off, int* __restrict__ cursor)
{
    __shared__ int sS[256];
    __shared__ int sTop;
    const int t = threadIdx.x;
    if (t < 64) {                       // wave 0: exclusive scan of partials
        int v = (t < SCAN_BLOCKS) ? partial[t] : 0;
        int inc = v;
        for (int o = 1; o < 64; o <<= 1) {
            int u = __shfl_up(inc, o);
            if (t >= o) inc += u;
        }
        if (t == blockIdx.x) sTop = inc - v;
    }
    const int base = blockIdx.x * 1000;
    int4 d = make_int4(0, 0, 0, 0);
    int local = 0;
    if (t < 250) {
        d = ((const int4*)(deg + base))[t];
        local = d.x + d.y + d.z + d.w;
    }
    sS[t] = local;
    __syncthreads();
    for (int o = 1; o < 256; o <<= 1) {
        int v = sS[t];
        int add = (t >= o) ? sS[t - o] : 0;
        __syncthreads();
        sS[t] = v + add;
        __syncthreads();
    }
    if (t < 250) {
        int p = sTop + sS[t] - local;   // exclusive prefix
        int4 o4 = make_int4(p, p + d.x, p + d.x + d.y, p + d.x + d.y + d.z);
        ((int4*)(off + base))[t] = o4;
        ((int4*)(cursor + base))[t] = o4;
    }
    if (blockIdx.x == 0 && t == 0) off[N_NODES] = N_EDGES;
}

// dst-sorted source index list only (3.2 MB random 4B writes)
__global__ __launch_bounds__(256) void scatter_src_kernel(
    const int* __restrict__ ei, int* __restrict__ cursor, int* __restrict__ ssrc)
{
    int i = blockIdx.x * 256 + threadIdx.x;
    const int stride = gridDim.x * 256;
    for (; i < N_EDGES; i += stride) {
        const int src = ei[i];
        const int d = ei[N_EDGES + i];
        const int pos = atomicAdd(&cursor[d], 1);
        ssrc[pos] = src;
    }
}

// ---------------------------------------------------------------------------
// Pure gather: pre[node] = x[node] + sum_{e: dst=node} x[src[e]].
// No LDS, no weights -> full occupancy; 8-wide software pipeline so ~8 row
// gathers stay in flight per wave; bounds-guarded tail (no over-read).
__global__ __launch_bounds__(256) void gather_kernel(
    const float* __restrict__ x, const int* __restrict__ off,
    const int* __restrict__ ssrc, float* __restrict__ pre)
{
    const int f = threadIdx.x & 63;
    const int w = threadIdx.x >> 6;
    const int nwv = gridDim.x * 4;
    for (int node = blockIdx.x * 4 + w; node < N_NODES; node += nwv) {
        const int start = __builtin_amdgcn_readfirstlane(off[node]);
        const int n     = __builtin_amdgcn_readfirstlane(off[node + 1]) - start;
        const int* sp = ssrc + start;
        float s = x[(size_t)node * D + f];
        int it = 0;
        if (n >= 8) {
            int a0 = sp[0], a1 = sp[1], a2 = sp[2], a3 = sp[3];
            int a4 = sp[4], a5 = sp[5], a6 = sp[6], a7 = sp[7];
            for (; it + 16 <= n; it += 8) {
                const int b0 = sp[it + 8],  b1 = sp[it + 9];
                const int b2 = sp[it + 10], b3 = sp[it + 11];
                const int b4 = sp[it + 12], b5 = sp[it + 13];
                const int b6 = sp[it + 14], b7 = sp[it + 15];
                s += x[(size_t)a0 * D + f]; s += x[(size_t)a1 * D + f];
                s += x[(size_t)a2 * D + f]; s += x[(size_t)a3 * D + f];
                s += x[(size_t)a4 * D + f]; s += x[(size_t)a5 * D + f];
                s += x[(size_t)a6 * D + f]; s += x[(size_t)a7 * D + f];
                a0 = b0; a1 = b1; a2 = b2; a3 = b3;
                a4 = b4; a5 = b5; a6 = b6; a7 = b7;
            }
            s += x[(size_t)a0 * D + f]; s += x[(size_t)a1 * D + f];
            s += x[(size_t)a2 * D + f]; s += x[(size_t)a3 * D + f];
            s += x[(size_t)a4 * D + f]; s += x[(size_t)a5 * D + f];
            s += x[(size_t)a6 * D + f]; s += x[(size_t)a7 * D + f];
            it += 8;
        }
        const int m = n - it;           // 0..7 remaining
        if (m > 0) {
            const int* sp2 = sp + it;
            // bounds-guarded index loads; issue all 7 x-row loads in parallel
            // with clamped (valid) indices, mask the adds.
            const int i0 = sp2[0];                   // m >= 1 always here
            const int i1 = (1 < m) ? sp2[1] : node;
            const int i2 = (2 < m) ? sp2[2] : node;
            const int i3 = (3 < m) ? sp2[3] : node;
            const int i4 = (4 < m) ? sp2[4] : node;
            const int i5 = (5 < m) ? sp2[5] : node;
            const int i6 = (6 < m) ? sp2[6] : node;
            const float v0 = x[(size_t)i0 * D + f];
            const float v1 = x[(size_t)i1 * D + f];
            const float v2 = x[(size_t)i2 * D + f];
            const float v3 = x[(size_t)i3 * D + f];
            const float v4 = x[(size_t)i4 * D + f];
            const float v5 = x[(size_t)i5 * D + f];
            const float v6 = x[(size_t)i6 * D + f];
            s += v0;
            s += (1 < m) ? v1 : 0.f;
            s += (2 < m) ? v2 : 0.f;
            s += (3 < m) ? v3 : 0.f;
            s += (4 < m) ? v4 : 0.f;
            s += (5 < m) ? v5 : 0.f;
            s += (6 < m) ? v6 : 0.f;
        }
        pre[(size_t)node * D + f] = s;
    }
}

// ---------------------------------------------------------------------------
// Streaming MLP1 + BN stats: h = (pre + deg*be + aggEA@We) @ W1 + b1
__global__ __launch_bounds__(256) void mlp1_kernel(
    const float* __restrict__ pre, const float* __restrict__ aggEA,
    const int* __restrict__ deg,
    const float* __restrict__ We, const float* __restrict__ be,
    const float* __restrict__ W1, const float* __restrict__ b1,
    float* __restrict__ h, float* __restrict__ sums, float* __restrict__ sumsq)
{
    __shared__ float sWe[ED][D];     // 8 KB
    __shared__ float sW1[D][D];      // 16 KB
    __shared__ float sRed[2][4][D];  // 2 KB

    const int tid = threadIdx.x;
    for (int i = tid; i < ED * D; i += 256) sWe[i >> 6][i & 63] = We[i];
    for (int i = tid; i < D * D; i += 256) sW1[i >> 6][i & 63] = W1[i];
    const int f = tid & 63;
    const int w = tid >> 6;
    const float be_f = be[f], b1_f = b1[f];
    float psum = 0.f, psq = 0.f;
    __syncthreads();

    const int nwv = gridDim.x * 4;
    for (int node = blockIdx.x * 4 + w; node < N_NODES; node += nwv) {
        const float ae = aggEA[(size_t)node * ED + (f & 31)];   // lanes 32-63 duplicate
        float val = pre[(size_t)node * D + f] + (float)deg[node] * be_f;
        #pragma unroll
        for (int k = 0; k < ED; ++k) val += __shfl(ae, k) * sWe[k][f];
        float hacc = b1_f;
        #pragma unroll
        for (int k = 0; k < D; ++k) hacc += __shfl(val, k) * sW1[k][f];
        h[(size_t)node * D + f] = hacc;
        psum += hacc;
        psq += hacc * hacc;
    }
    sRed[0][w][f] = psum;
    sRed[1][w][f] = psq;
    __syncthreads();
    if (w == 0) {
        const float s = sRed[0][0][f] + sRed[0][1][f] + sRed[0][2][f] + sRed[0][3][f];
        const float q = sRed[1][0][f] + sRed[1][1][f] + sRed[1][2][f] + sRed[1][3][f];
        unsafeAtomicAdd(&sums[f], s);
        unsafeAtomicAdd(&sumsq[f], q);
    }
}

// ---------------------------------------------------------------------------
// MLP2 with BN stats finalized inline per block: out = relu(h*sc+sh) @ W2 + b2
__global__ __launch_bounds__(256) void mlp2_kernel(
    const float* __restrict__ h, const float* __restrict__ W2,
    const float* __restrict__ b2, const float* __restrict__ sums,
    const float* __restrict__ sumsq, const float* __restrict__ gamma,
    const float* __restrict__ beta, float* __restrict__ out)
{
    __shared__ float sW2[D][D];  // 16 KB
    const int tid = threadIdx.x;
    for (int i = tid; i < D * D; i += 256) sW2[i >> 6][i & 63] = W2[i];
    const int f = tid & 63;
    const int w = tid >> 6;
    const float inv_n = 1.0f / (float)N_NODES;
    const float mean = sums[f] * inv_n;
    const float var  = sumsq[f] * inv_n - mean * mean;   // biased, like jnp.var
    const float sc   = gamma[f] * rsqrtf(var + BN_EPS);
    const float sh   = beta[f] - mean * sc;
    const float b    = b2[f];
    __syncthreads();

    const int gstride = gridDim.x * 4;
    for (int node0 = blockIdx.x * 4; node0 < N_NODES; node0 += gstride) {
        const int node = node0 + w;
        if (node < N_NODES) {
            float v = h[(size_t)node * D + f] * sc + sh;
            v = v > 0.f ? v : 0.f;
            float acc = b;
            #pragma unroll
            for (int k = 0; k < D; ++k) acc += __shfl(v, k) * sW2[k][f];
            out[(size_t)node * D + f] = acc;
        }
    }
}

// ---------------------------------------------------------------------------
extern "C" void kernel_launch(void* const* d_in, const int* in_sizes, int n_in,
                              void* d_out, int out_size, void* d_ws, size_t ws_size,
                              hipStream_t stream) {
    const float* x     = (const float*)d_in[0];
    const int*   ei    = (const int*)  d_in[1];   // [2, E] int32
    const float* ea    = (const float*)d_in[2];
    const float* We    = (const float*)d_in[3];
    const float* be    = (const float*)d_in[4];
    const float* W1    = (const float*)d_in[5];
    const float* b1    = (const float*)d_in[6];
    const float* gamma = (const float*)d_in[7];
    const float* beta  = (const float*)d_in[8];
    const float* W2    = (const float*)d_in[9];
    const float* b2    = (const float*)d_in[10];

    float* ws      = (float*)d_ws;
    float* sums    = ws + WS_SUMS;
    float* sumsq   = ws + WS_SUMSQ;
    int*   partial = (int*)(ws + WS_PART);
    int*   deg     = (int*)(ws + WS_DEG);
    float* aggEA   = ws + WS_AGGEA;
    int*   off     = (int*)(ws + WS_OFF);
    int*   cursor  = (int*)(ws + WS_CURSOR);
    int*   ssrc    = (int*)(ws + WS_SRC);
    float* pre     = ws + WS_PRE;
    float* h       = ws + WS_H;

    hipMemsetAsync(ws, 0, (size_t)WS_ZERO_END * sizeof(float), stream);

    edge_ea_kernel     <<<2048, 256, 0, stream>>>(ei + N_EDGES, ea, aggEA, deg);
    scan_partial_kernel<<<SCAN_BLOCKS, 256, 0, stream>>>(deg, partial);
    scan_write_kernel  <<<SCAN_BLOCKS, 256, 0, stream>>>(deg, partial, off, cursor);
    scatter_src_kernel <<<1024, 256, 0, stream>>>(ei, cursor, ssrc);
    gather_kernel      <<<2048, 256, 0, stream>>>(x, off, ssrc, pre);
    mlp1_kernel        <<<1536, 256, 0, stream>>>(pre, aggEA, deg, We, be, W1, b1,
                                                  h, sums, sumsq);
    mlp2_kernel        <<<1024, 256, 0, stream>>>(h, W2, b2, sums, sumsq,
                                                  gamma, beta, (float*)d_out);
}

// Round 4
// 417.159 us; speedup vs baseline: 1.7146x; 1.7146x over previous
//
#include <hip/hip_runtime.h>

#define N_NODES 50000
#define N_EDGES 800000
#define D 64          // D_IN == D_OUT
#define ED 32         // EDGE_DIM
#define BN_EPS 1e-5f

// ---- workspace layout (32-bit word indices) -------------------------------
#define WS_SUMS     0
#define WS_SUMSQ    64
#define WS_PART     128                       // 64 ints: scan partials
#define WS_DEG      256
#define WS_ZERO_END (WS_DEG + N_NODES)        // memset [0, here) ~201 KB
#define WS_OFF      WS_ZERO_END               // 50256
#define WS_CURSOR   (WS_OFF + N_NODES + 4)    // 100260
#define WS_SRC2     (WS_CURSOR + N_NODES)     // 150260 (byte 601040, 8B ok)
#define WS_AGGEA    (WS_SRC2 + 2 * N_EDGES)   // 1750260 (byte 7001040, 16B ok)
#define WS_PRE      (WS_AGGEA + N_NODES * ED) // 3350260
#define WS_H        (WS_PRE + N_NODES * D)    // 6550260
// total = WS_H + N_NODES*D = 9750260 words ~ 39 MB (ws proved >= 68 MB)

#define SCAN_BLOCKS 50   // 50 x 1000 = N_NODES exactly

// ---------------------------------------------------------------------------
// degree histogram (int atomics, ~800k ops — measured OK in baseline)
__global__ __launch_bounds__(256) void count_kernel(
    const int* __restrict__ dst, int* __restrict__ deg)
{
    int i = blockIdx.x * 256 + threadIdx.x;
    const int stride = gridDim.x * 256;
    for (; i < N_EDGES / 4; i += stride) {
        int4 d = ((const int4*)dst)[i];
        atomicAdd(&deg[d.x], 1);
        atomicAdd(&deg[d.y], 1);
        atomicAdd(&deg[d.z], 1);
        atomicAdd(&deg[d.w], 1);
    }
}

// per-block partial sums over 1000 ints (coalesced int4)
__global__ __launch_bounds__(256) void scan_partial_kernel(
    const int* __restrict__ deg, int* __restrict__ partial)
{
    __shared__ int sR[256];
    const int t = threadIdx.x;
    const int base = blockIdx.x * 1000;
    int local = 0;
    if (t < 250) {
        int4 d = ((const int4*)(deg + base))[t];
        local = d.x + d.y + d.z + d.w;
    }
    sR[t] = local;
    __syncthreads();
    for (int o = 128; o > 0; o >>= 1) {
        if (t < o) sR[t] += sR[t + o];
        __syncthreads();
    }
    if (t == 0) partial[blockIdx.x] = sR[0];
}

// block-local scan + in-kernel top scan of the 50 partials; writes off & cursor
__global__ __launch_bounds__(256) void scan_write_kernel(
    const int* __restrict__ deg, const int* __restrict__ partial,
    int* __restrict__ off, int* __restrict__ cursor)
{
    __shared__ int sS[256];
    __shared__ int sTop;
    const int t = threadIdx.x;
    if (t < 64) {                       // wave 0: exclusive scan of partials
        int v = (t < SCAN_BLOCKS) ? partial[t] : 0;
        int inc = v;
        for (int o = 1; o < 64; o <<= 1) {
            int u = __shfl_up(inc, o);
            if (t >= o) inc += u;
        }
        if (t == blockIdx.x) sTop = inc - v;
    }
    const int base = blockIdx.x * 1000;
    int4 d = make_int4(0, 0, 0, 0);
    int local = 0;
    if (t < 250) {
        d = ((const int4*)(deg + base))[t];
        local = d.x + d.y + d.z + d.w;
    }
    sS[t] = local;
    __syncthreads();
    for (int o = 1; o < 256; o <<= 1) {
        int v = sS[t];
        int add = (t >= o) ? sS[t - o] : 0;
        __syncthreads();
        sS[t] = v + add;
        __syncthreads();
    }
    if (t < 250) {
        int p = sTop + sS[t] - local;   // exclusive prefix
        int4 o4 = make_int4(p, p + d.x, p + d.x + d.y, p + d.x + d.y + d.z);
        ((int4*)(off + base))[t] = o4;
        ((int4*)(cursor + base))[t] = o4;
    }
    if (blockIdx.x == 0 && t == 0) off[N_NODES] = N_EDGES;
}

// dst-sorted (eid, src) pairs (6.4 MB random 8B writes)
__global__ __launch_bounds__(256) void scatter_kernel(
    const int* __restrict__ ei, int* __restrict__ cursor, int2* __restrict__ sorted)
{
    int i = blockIdx.x * 256 + threadIdx.x;
    const int stride = gridDim.x * 256;
    for (; i < N_EDGES; i += stride) {
        const int src = ei[i];
        const int d = ei[N_EDGES + i];
        const int pos = atomicAdd(&cursor[d], 1);
        sorted[pos] = make_int2(i, src);
    }
}

// ---------------------------------------------------------------------------
// Pure gather, no LDS -> full occupancy. Per node:
//   pre[node]   = x[node] + sum_e x[src[e]]        (256B rows, lanes 0..63)
//   aggEA[node] = sum_e ea[eid[e]]                 (128B rows, 2 edges/instr)
// 8-deep software pipeline: 8 x-loads + 4 ea-loads in flight per group.
__global__ __launch_bounds__(256) void agg_kernel(
    const float* __restrict__ x, const float* __restrict__ ea,
    const int* __restrict__ off, const int2* __restrict__ sorted,
    float* __restrict__ pre, float* __restrict__ aggEA)
{
    const int f = threadIdx.x & 63;
    const int w = threadIdx.x >> 6;
    const int fe = f & 31;
    const bool lo = (f < 32);
    const int nwv = gridDim.x * 4;
    for (int node = blockIdx.x * 4 + w; node < N_NODES; node += nwv) {
        const int start = __builtin_amdgcn_readfirstlane(off[node]);
        const int n     = __builtin_amdgcn_readfirstlane(off[node + 1]) - start;
        const int2* sp = sorted + start;
        float s = x[(size_t)node * D + f];
        float ax = 0.f, ay = 0.f;
        int it = 0;
        if (n >= 8) {
            int2 c0 = sp[0], c1 = sp[1], c2 = sp[2], c3 = sp[3];
            int2 c4 = sp[4], c5 = sp[5], c6 = sp[6], c7 = sp[7];
            for (; it + 16 <= n; it += 8) {
                const int2 n0 = sp[it + 8],  n1 = sp[it + 9];
                const int2 n2 = sp[it + 10], n3 = sp[it + 11];
                const int2 n4 = sp[it + 12], n5 = sp[it + 13];
                const int2 n6 = sp[it + 14], n7 = sp[it + 15];
                s += x[(size_t)c0.y * D + f]; s += x[(size_t)c1.y * D + f];
                s += x[(size_t)c2.y * D + f]; s += x[(size_t)c3.y * D + f];
                s += x[(size_t)c4.y * D + f]; s += x[(size_t)c5.y * D + f];
                s += x[(size_t)c6.y * D + f]; s += x[(size_t)c7.y * D + f];
                ax += ea[(size_t)(lo ? c0.x : c1.x) * ED + fe];
                ax += ea[(size_t)(lo ? c2.x : c3.x) * ED + fe];
                ay += ea[(size_t)(lo ? c4.x : c5.x) * ED + fe];
                ay += ea[(size_t)(lo ? c6.x : c7.x) * ED + fe];
                c0 = n0; c1 = n1; c2 = n2; c3 = n3;
                c4 = n4; c5 = n5; c6 = n6; c7 = n7;
            }
            s += x[(size_t)c0.y * D + f]; s += x[(size_t)c1.y * D + f];
            s += x[(size_t)c2.y * D + f]; s += x[(size_t)c3.y * D + f];
            s += x[(size_t)c4.y * D + f]; s += x[(size_t)c5.y * D + f];
            s += x[(size_t)c6.y * D + f]; s += x[(size_t)c7.y * D + f];
            ax += ea[(size_t)(lo ? c0.x : c1.x) * ED + fe];
            ax += ea[(size_t)(lo ? c2.x : c3.x) * ED + fe];
            ay += ea[(size_t)(lo ? c4.x : c5.x) * ED + fe];
            ay += ea[(size_t)(lo ? c6.x : c7.x) * ED + fe];
            it += 8;
        }
        for (; it < n; ++it) {               // tail: 0..7 edges
            const int2 p = sp[it];
            s += x[(size_t)p.y * D + f];
            if (lo) ax += ea[(size_t)p.x * ED + fe];
        }
        pre[(size_t)node * D + f] = s;
        ax += ay;
        ax += __shfl_xor(ax, 32);            // even-edge + odd-edge halves
        if (lo) aggEA[(size_t)node * ED + fe] = ax;
    }
}

// ---------------------------------------------------------------------------
// Streaming MLP1 + BN stats: h = (pre + deg*be + aggEA@We) @ W1 + b1
__global__ __launch_bounds__(256) void mlp1_kernel(
    const float* __restrict__ pre, const float* __restrict__ aggEA,
    const int* __restrict__ deg,
    const float* __restrict__ We, const float* __restrict__ be,
    const float* __restrict__ W1, const float* __restrict__ b1,
    float* __restrict__ h, float* __restrict__ sums, float* __restrict__ sumsq)
{
    __shared__ float sWe[ED][D];     // 8 KB
    __shared__ float sW1[D][D];      // 16 KB
    __shared__ float sRed[2][4][D];  // 2 KB

    const int tid = threadIdx.x;
    for (int i = tid; i < ED * D; i += 256) sWe[i >> 6][i & 63] = We[i];
    for (int i = tid; i < D * D; i += 256) sW1[i >> 6][i & 63] = W1[i];
    const int f = tid & 63;
    const int w = tid >> 6;
    const float be_f = be[f], b1_f = b1[f];
    float psum = 0.f, psq = 0.f;
    __syncthreads();

    const int nwv = gridDim.x * 4;
    for (int node = blockIdx.x * 4 + w; node < N_NODES; node += nwv) {
        const float ae = aggEA[(size_t)node * ED + (f & 31)];   // lanes 32-63 duplicate
        float val = pre[(size_t)node * D + f] + (float)deg[node] * be_f;
        #pragma unroll
        for (int k = 0; k < ED; ++k) val += __shfl(ae, k) * sWe[k][f];
        float hacc = b1_f;
        #pragma unroll
        for (int k = 0; k < D; ++k) hacc += __shfl(val, k) * sW1[k][f];
        h[(size_t)node * D + f] = hacc;
        psum += hacc;
        psq += hacc * hacc;
    }
    sRed[0][w][f] = psum;
    sRed[1][w][f] = psq;
    __syncthreads();
    if (w == 0) {
        const float s = sRed[0][0][f] + sRed[0][1][f] + sRed[0][2][f] + sRed[0][3][f];
        const float q = sRed[1][0][f] + sRed[1][1][f] + sRed[1][2][f] + sRed[1][3][f];
        unsafeAtomicAdd(&sums[f], s);
        unsafeAtomicAdd(&sumsq[f], q);
    }
}

// ---------------------------------------------------------------------------
// MLP2 with BN stats finalized inline per block: out = relu(h*sc+sh) @ W2 + b2
__global__ __launch_bounds__(256) void mlp2_kernel(
    const float* __restrict__ h, const float* __restrict__ W2,
    const float* __restrict__ b2, const float* __restrict__ sums,
    const float* __restrict__ sumsq, const float* __restrict__ gamma,
    const float* __restrict__ beta, float* __restrict__ out)
{
    __shared__ float sW2[D][D];  // 16 KB
    const int tid = threadIdx.x;
    for (int i = tid; i < D * D; i += 256) sW2[i >> 6][i & 63] = W2[i];
    const int f = tid & 63;
    const int w = tid >> 6;
    const float inv_n = 1.0f / (float)N_NODES;
    const float mean = sums[f] * inv_n;
    const float var  = sumsq[f] * inv_n - mean * mean;   // biased, like jnp.var
    const float sc   = gamma[f] * rsqrtf(var + BN_EPS);
    const float sh   = beta[f] - mean * sc;
    const float b    = b2[f];
    __syncthreads();

    const int gstride = gridDim.x * 4;
    for (int node0 = blockIdx.x * 4; node0 < N_NODES; node0 += gstride) {
        const int node = node0 + w;
        if (node < N_NODES) {
            float v = h[(size_t)node * D + f] * sc + sh;
            v = v > 0.f ? v : 0.f;
            float acc = b;
            #pragma unroll
            for (int k = 0; k < D; ++k) acc += __shfl(v, k) * sW2[k][f];
            out[(size_t)node * D + f] = acc;
        }
    }
}

// ---------------------------------------------------------------------------
extern "C" void kernel_launch(void* const* d_in, const int* in_sizes, int n_in,
                              void* d_out, int out_size, void* d_ws, size_t ws_size,
                              hipStream_t stream) {
    const float* x     = (const float*)d_in[0];
    const int*   ei    = (const int*)  d_in[1];   // [2, E] int32
    const float* ea    = (const float*)d_in[2];
    const float* We    = (const float*)d_in[3];
    const float* be    = (const float*)d_in[4];
    const float* W1    = (const float*)d_in[5];
    const float* b1    = (const float*)d_in[6];
    const float* gamma = (const float*)d_in[7];
    const float* beta  = (const float*)d_in[8];
    const float* W2    = (const float*)d_in[9];
    const float* b2    = (const float*)d_in[10];

    float* ws      = (float*)d_ws;
    float* sums    = ws + WS_SUMS;
    float* sumsq   = ws + WS_SUMSQ;
    int*   partial = (int*)(ws + WS_PART);
    int*   deg     = (int*)(ws + WS_DEG);
    int*   off     = (int*)(ws + WS_OFF);
    int*   cursor  = (int*)(ws + WS_CURSOR);
    int2*  sorted2 = (int2*)(ws + WS_SRC2);
    float* aggEA   = ws + WS_AGGEA;
    float* pre     = ws + WS_PRE;
    float* h       = ws + WS_H;

    hipMemsetAsync(ws, 0, (size_t)WS_ZERO_END * sizeof(float), stream);

    count_kernel       <<<784, 256, 0, stream>>>(ei + N_EDGES, deg);
    scan_partial_kernel<<<SCAN_BLOCKS, 256, 0, stream>>>(deg, partial);
    scan_write_kernel  <<<SCAN_BLOCKS, 256, 0, stream>>>(deg, partial, off, cursor);
    scatter_kernel     <<<1024, 256, 0, stream>>>(ei, cursor, sorted2);
    agg_kernel         <<<2048, 256, 0, stream>>>(x, ea, off, sorted2, pre, aggEA);
    mlp1_kernel        <<<1536, 256, 0, stream>>>(pre, aggEA, deg, We, be, W1, b1,
                                                  h, sums, sumsq);
    mlp2_kernel        <<<1024, 256, 0, stream>>>(h, W2, b2, sums, sumsq,
                                                  gamma, beta, (float*)d_out);
}

// Round 5
// 412.206 us; speedup vs baseline: 1.7352x; 1.0120x over previous
//
#include <hip/hip_runtime.h>

#define N_NODES 50000
#define N_EDGES 800000
#define D 64          // D_IN == D_OUT
#define ED 32         // EDGE_DIM
#define BN_EPS 1e-5f

// ---- workspace layout (32-bit word indices) -------------------------------
#define WS_SUMS     0
#define WS_SUMSQ    64
#define WS_PART     128                       // 64 ints: scan partials
#define WS_DEG      256
#define WS_ZERO_END (WS_DEG + N_NODES)        // memset [0, here) ~201 KB
#define WS_OFF      WS_ZERO_END               // 50256
#define WS_CURSOR   (WS_OFF + N_NODES + 4)    // 100260
#define WS_SRC2     (WS_CURSOR + N_NODES)     // 150260 (byte 601040, 8B ok)
#define WS_AGGEA    (WS_SRC2 + 2 * N_EDGES)   // 1750260 (byte 7001040, 16B ok)
#define WS_PRE      (WS_AGGEA + N_NODES * ED) // 3350260 (byte 13401040, 16B ok)
#define WS_H        (WS_PRE + N_NODES * D)    // 6550260 (byte 26201040, 16B ok)
// total = WS_H + N_NODES*D = 9750260 words ~ 39 MB (ws proved >= 68 MB)

#define SCAN_BLOCKS 50   // 50 x 1000 = N_NODES exactly
#define N_GRP ((N_NODES + 63) / 64)   // 782 wave-tasks for lane=node kernels

// ---------------------------------------------------------------------------
// degree histogram (int atomics, ~800k ops — measured OK in baseline)
__global__ __launch_bounds__(256) void count_kernel(
    const int* __restrict__ dst, int* __restrict__ deg)
{
    int i = blockIdx.x * 256 + threadIdx.x;
    const int stride = gridDim.x * 256;
    for (; i < N_EDGES / 4; i += stride) {
        int4 d = ((const int4*)dst)[i];
        atomicAdd(&deg[d.x], 1);
        atomicAdd(&deg[d.y], 1);
        atomicAdd(&deg[d.z], 1);
        atomicAdd(&deg[d.w], 1);
    }
}

// per-block partial sums over 1000 ints (coalesced int4)
__global__ __launch_bounds__(256) void scan_partial_kernel(
    const int* __restrict__ deg, int* __restrict__ partial)
{
    __shared__ int sR[256];
    const int t = threadIdx.x;
    const int base = blockIdx.x * 1000;
    int local = 0;
    if (t < 250) {
        int4 d = ((const int4*)(deg + base))[t];
        local = d.x + d.y + d.z + d.w;
    }
    sR[t] = local;
    __syncthreads();
    for (int o = 128; o > 0; o >>= 1) {
        if (t < o) sR[t] += sR[t + o];
        __syncthreads();
    }
    if (t == 0) partial[blockIdx.x] = sR[0];
}

// block-local scan + in-kernel top scan of the 50 partials; writes off & cursor
__global__ __launch_bounds__(256) void scan_write_kernel(
    const int* __restrict__ deg, const int* __restrict__ partial,
    int* __restrict__ off, int* __restrict__ cursor)
{
    __shared__ int sS[256];
    __shared__ int sTop;
    const int t = threadIdx.x;
    if (t < 64) {                       // wave 0: exclusive scan of partials
        int v = (t < SCAN_BLOCKS) ? partial[t] : 0;
        int inc = v;
        for (int o = 1; o < 64; o <<= 1) {
            int u = __shfl_up(inc, o);
            if (t >= o) inc += u;
        }
        if (t == blockIdx.x) sTop = inc - v;
    }
    const int base = blockIdx.x * 1000;
    int4 d = make_int4(0, 0, 0, 0);
    int local = 0;
    if (t < 250) {
        d = ((const int4*)(deg + base))[t];
        local = d.x + d.y + d.z + d.w;
    }
    sS[t] = local;
    __syncthreads();
    for (int o = 1; o < 256; o <<= 1) {
        int v = sS[t];
        int add = (t >= o) ? sS[t - o] : 0;
        __syncthreads();
        sS[t] = v + add;
        __syncthreads();
    }
    if (t < 250) {
        int p = sTop + sS[t] - local;   // exclusive prefix
        int4 o4 = make_int4(p, p + d.x, p + d.x + d.y, p + d.x + d.y + d.z);
        ((int4*)(off + base))[t] = o4;
        ((int4*)(cursor + base))[t] = o4;
    }
    if (blockIdx.x == 0 && t == 0) off[N_NODES] = N_EDGES;
}

// dst-sorted (eid, src) pairs (6.4 MB random 8B writes)
__global__ __launch_bounds__(256) void scatter_kernel(
    const int* __restrict__ ei, int* __restrict__ cursor, int2* __restrict__ sorted)
{
    int i = blockIdx.x * 256 + threadIdx.x;
    const int stride = gridDim.x * 256;
    for (; i < N_EDGES; i += stride) {
        const int src = ei[i];
        const int d = ei[N_EDGES + i];
        const int pos = atomicAdd(&cursor[d], 1);
        sorted[pos] = make_int2(i, src);
    }
}

// ---------------------------------------------------------------------------
// Pure gather, no LDS -> full occupancy. Per node (wave):
//   pre[node]   = x[node] + sum_e x[src[e]]        (256B rows, lanes 0..63)
//   aggEA[node] = sum_e ea[eid[e]]                 (128B rows, 2 edges/instr)
__global__ __launch_bounds__(256) void agg_kernel(
    const float* __restrict__ x, const float* __restrict__ ea,
    const int* __restrict__ off, const int2* __restrict__ sorted,
    float* __restrict__ pre, float* __restrict__ aggEA)
{
    const int f = threadIdx.x & 63;
    const int w = threadIdx.x >> 6;
    const int fe = f & 31;
    const bool lo = (f < 32);
    const int nwv = gridDim.x * 4;
    for (int node = blockIdx.x * 4 + w; node < N_NODES; node += nwv) {
        const int start = __builtin_amdgcn_readfirstlane(off[node]);
        const int n     = __builtin_amdgcn_readfirstlane(off[node + 1]) - start;
        const int2* sp = sorted + start;
        float s = x[(size_t)node * D + f];
        float ax = 0.f, ay = 0.f;
        int it = 0;
        if (n >= 8) {
            int2 c0 = sp[0], c1 = sp[1], c2 = sp[2], c3 = sp[3];
            int2 c4 = sp[4], c5 = sp[5], c6 = sp[6], c7 = sp[7];
            for (; it + 16 <= n; it += 8) {
                const int2 n0 = sp[it + 8],  n1 = sp[it + 9];
                const int2 n2 = sp[it + 10], n3 = sp[it + 11];
                const int2 n4 = sp[it + 12], n5 = sp[it + 13];
                const int2 n6 = sp[it + 14], n7 = sp[it + 15];
                s += x[(size_t)c0.y * D + f]; s += x[(size_t)c1.y * D + f];
                s += x[(size_t)c2.y * D + f]; s += x[(size_t)c3.y * D + f];
                s += x[(size_t)c4.y * D + f]; s += x[(size_t)c5.y * D + f];
                s += x[(size_t)c6.y * D + f]; s += x[(size_t)c7.y * D + f];
                ax += ea[(size_t)(lo ? c0.x : c1.x) * ED + fe];
                ax += ea[(size_t)(lo ? c2.x : c3.x) * ED + fe];
                ay += ea[(size_t)(lo ? c4.x : c5.x) * ED + fe];
                ay += ea[(size_t)(lo ? c6.x : c7.x) * ED + fe];
                c0 = n0; c1 = n1; c2 = n2; c3 = n3;
                c4 = n4; c5 = n5; c6 = n6; c7 = n7;
            }
            s += x[(size_t)c0.y * D + f]; s += x[(size_t)c1.y * D + f];
            s += x[(size_t)c2.y * D + f]; s += x[(size_t)c3.y * D + f];
            s += x[(size_t)c4.y * D + f]; s += x[(size_t)c5.y * D + f];
            s += x[(size_t)c6.y * D + f]; s += x[(size_t)c7.y * D + f];
            ax += ea[(size_t)(lo ? c0.x : c1.x) * ED + fe];
            ax += ea[(size_t)(lo ? c2.x : c3.x) * ED + fe];
            ay += ea[(size_t)(lo ? c4.x : c5.x) * ED + fe];
            ay += ea[(size_t)(lo ? c6.x : c7.x) * ED + fe];
            it += 8;
        }
        for (; it < n; ++it) {               // tail: 0..7 edges
            const int2 p = sp[it];
            s += x[(size_t)p.y * D + f];
            if (lo) ax += ea[(size_t)p.x * ED + fe];
        }
        pre[(size_t)node * D + f] = s;
        ax += ay;
        ax += __shfl_xor(ax, 32);            // even-edge + odd-edge halves
        if (lo) aggEA[(size_t)node * ED + fe] = ax;
    }
}

// ---------------------------------------------------------------------------
// MLP1, lane=node: each lane holds its node's 64-f32 row in registers.
// val = pre + deg*be + aggEA@We ; h = val@W1 + b1. Weights broadcast from LDS
// (wave-uniform ds_read_b128, conflict-free). 6144 independent FMAs/lane.
__global__ __launch_bounds__(256) void mlp1_kernel(
    const float* __restrict__ pre, const float* __restrict__ aggEA,
    const int* __restrict__ deg,
    const float* __restrict__ We, const float* __restrict__ be,
    const float* __restrict__ W1, const float* __restrict__ b1,
    float* __restrict__ h)
{
    __shared__ float4 sWe[ED][16];   // We[j][k]  8 KB
    __shared__ float4 sW1[D][16];    // W1[k][f] 16 KB
    __shared__ float4 sbe[16];
    __shared__ float4 sb1[16];
    const int tid = threadIdx.x;
    for (int i = tid; i < ED * 16; i += 256) sWe[i >> 4][i & 15] = ((const float4*)We)[i];
    for (int i = tid; i < D * 16; i += 256)  sW1[i >> 4][i & 15] = ((const float4*)W1)[i];
    if (tid < 16)       sbe[tid] = ((const float4*)be)[tid];
    else if (tid < 32)  sb1[tid - 16] = ((const float4*)b1)[tid - 16];
    __syncthreads();

    const int lane = tid & 63;
    const int w = tid >> 6;
    for (int grp = blockIdx.x * 4 + w; grp < N_GRP; grp += gridDim.x * 4) {
        const int node = grp * 64 + lane;
        if (node >= N_NODES) continue;
        float vv[D];
        #pragma unroll
        for (int i = 0; i < 16; ++i)
            ((float4*)vv)[i] = ((const float4*)(pre + (size_t)node * D))[i];
        float av[ED];
        #pragma unroll
        for (int i = 0; i < 8; ++i)
            ((float4*)av)[i] = ((const float4*)(aggEA + (size_t)node * ED))[i];
        const float dg = (float)deg[node];
        #pragma unroll
        for (int i = 0; i < 16; ++i) {
            const float4 b = sbe[i];
            vv[4*i+0] += dg * b.x; vv[4*i+1] += dg * b.y;
            vv[4*i+2] += dg * b.z; vv[4*i+3] += dg * b.w;
        }
        #pragma unroll
        for (int j = 0; j < ED; ++j) {
            const float aj = av[j];
            #pragma unroll
            for (int i = 0; i < 16; ++i) {
                const float4 wv = sWe[j][i];
                vv[4*i+0] += aj * wv.x; vv[4*i+1] += aj * wv.y;
                vv[4*i+2] += aj * wv.z; vv[4*i+3] += aj * wv.w;
            }
        }
        float hh[D];
        #pragma unroll
        for (int i = 0; i < 16; ++i) {
            const float4 b = sb1[i];
            hh[4*i+0] = b.x; hh[4*i+1] = b.y; hh[4*i+2] = b.z; hh[4*i+3] = b.w;
        }
        #pragma unroll
        for (int k = 0; k < D; ++k) {
            const float vk = vv[k];
            #pragma unroll
            for (int i = 0; i < 16; ++i) {
                const float4 wv = sW1[k][i];
                hh[4*i+0] += vk * wv.x; hh[4*i+1] += vk * wv.y;
                hh[4*i+2] += vk * wv.z; hh[4*i+3] += vk * wv.w;
            }
        }
        #pragma unroll
        for (int i = 0; i < 16; ++i)
            ((float4*)(h + (size_t)node * D))[i] = ((float4*)hh)[i];
    }
}

// ---------------------------------------------------------------------------
// BN stats: coalesced streaming pass over h (lane=feature), per-block reduce.
__global__ __launch_bounds__(256) void bn_stats_kernel(
    const float* __restrict__ h, float* __restrict__ sums, float* __restrict__ sumsq)
{
    __shared__ float sRed[2][4][D];
    const int f = threadIdx.x & 63;
    const int w = threadIdx.x >> 6;
    float ps = 0.f, pq = 0.f;
    const int nwv = gridDim.x * 4;
    for (int node = blockIdx.x * 4 + w; node < N_NODES; node += nwv) {
        const float v = h[(size_t)node * D + f];
        ps += v;
        pq += v * v;
    }
    sRed[0][w][f] = ps;
    sRed[1][w][f] = pq;
    __syncthreads();
    if (w == 0) {
        const float s = sRed[0][0][f] + sRed[0][1][f] + sRed[0][2][f] + sRed[0][3][f];
        const float q = sRed[1][0][f] + sRed[1][1][f] + sRed[1][2][f] + sRed[1][3][f];
        unsafeAtomicAdd(&sums[f], s);
        unsafeAtomicAdd(&sumsq[f], q);
    }
}

// ---------------------------------------------------------------------------
// MLP2, lane=node: out = relu(h*sc+sh) @ W2 + b2, BN finalized into LDS.
__global__ __launch_bounds__(256) void mlp2_kernel(
    const float* __restrict__ h, const float* __restrict__ W2,
    const float* __restrict__ b2, const float* __restrict__ sums,
    const float* __restrict__ sumsq, const float* __restrict__ gamma,
    const float* __restrict__ beta, float* __restrict__ out)
{
    __shared__ float4 sW2[D][16];    // 16 KB
    __shared__ float4 sb2[16];
    __shared__ float ssc[D];
    __shared__ float ssh[D];
    const int tid = threadIdx.x;
    for (int i = tid; i < D * 16; i += 256) sW2[i >> 4][i & 15] = ((const float4*)W2)[i];
    if (tid < 16) sb2[tid] = ((const float4*)b2)[tid];
    if (tid < 64) {
        const float inv_n = 1.0f / (float)N_NODES;
        const float mean = sums[tid] * inv_n;
        const float var  = sumsq[tid] * inv_n - mean * mean;   // biased, like jnp.var
        const float sc   = gamma[tid] * rsqrtf(var + BN_EPS);
        ssc[tid] = sc;
        ssh[tid] = beta[tid] - mean * sc;
    }
    __syncthreads();

    const int lane = tid & 63;
    const int w = tid >> 6;
    for (int grp = blockIdx.x * 4 + w; grp < N_GRP; grp += gridDim.x * 4) {
        const int node = grp * 64 + lane;
        if (node >= N_NODES) continue;
        float vv[D];
        #pragma unroll
        for (int i = 0; i < 16; ++i)
            ((float4*)vv)[i] = ((const float4*)(h + (size_t)node * D))[i];
        #pragma unroll
        for (int i = 0; i < 16; ++i) {
            const float4 c = ((const float4*)ssc)[i];
            const float4 s = ((const float4*)ssh)[i];
            float t;
            t = vv[4*i+0] * c.x + s.x; vv[4*i+0] = t > 0.f ? t : 0.f;
            t = vv[4*i+1] * c.y + s.y; vv[4*i+1] = t > 0.f ? t : 0.f;
            t = vv[4*i+2] * c.z + s.z; vv[4*i+2] = t > 0.f ? t : 0.f;
            t = vv[4*i+3] * c.w + s.w; vv[4*i+3] = t > 0.f ? t : 0.f;
        }
        float oo[D];
        #pragma unroll
        for (int i = 0; i < 16; ++i) {
            const float4 b = sb2[i];
            oo[4*i+0] = b.x; oo[4*i+1] = b.y; oo[4*i+2] = b.z; oo[4*i+3] = b.w;
        }
        #pragma unroll
        for (int k = 0; k < D; ++k) {
            const float vk = vv[k];
            #pragma unroll
            for (int i = 0; i < 16; ++i) {
                const float4 wv = sW2[k][i];
                oo[4*i+0] += vk * wv.x; oo[4*i+1] += vk * wv.y;
                oo[4*i+2] += vk * wv.z; oo[4*i+3] += vk * wv.w;
            }
        }
        #pragma unroll
        for (int i = 0; i < 16; ++i)
            ((float4*)(out + (size_t)node * D))[i] = ((float4*)oo)[i];
    }
}

// ---------------------------------------------------------------------------
extern "C" void kernel_launch(void* const* d_in, const int* in_sizes, int n_in,
                              void* d_out, int out_size, void* d_ws, size_t ws_size,
                              hipStream_t stream) {
    const float* x     = (const float*)d_in[0];
    const int*   ei    = (const int*)  d_in[1];   // [2, E] int32
    const float* ea    = (const float*)d_in[2];
    const float* We    = (const float*)d_in[3];
    const float* be    = (const float*)d_in[4];
    const float* W1    = (const float*)d_in[5];
    const float* b1    = (const float*)d_in[6];
    const float* gamma = (const float*)d_in[7];
    const float* beta  = (const float*)d_in[8];
    const float* W2    = (const float*)d_in[9];
    const float* b2    = (const float*)d_in[10];

    float* ws      = (float*)d_ws;
    float* sums    = ws + WS_SUMS;
    float* sumsq   = ws + WS_SUMSQ;
    int*   partial = (int*)(ws + WS_PART);
    int*   deg     = (int*)(ws + WS_DEG);
    int*   off     = (int*)(ws + WS_OFF);
    int*   cursor  = (int*)(ws + WS_CURSOR);
    int2*  sorted2 = (int2*)(ws + WS_SRC2);
    float* aggEA   = ws + WS_AGGEA;
    float* pre     = ws + WS_PRE;
    float* h       = ws + WS_H;

    hipMemsetAsync(ws, 0, (size_t)WS_ZERO_END * sizeof(float), stream);

    count_kernel       <<<784, 256, 0, stream>>>(ei + N_EDGES, deg);
    scan_partial_kernel<<<SCAN_BLOCKS, 256, 0, stream>>>(deg, partial);
    scan_write_kernel  <<<SCAN_BLOCKS, 256, 0, stream>>>(deg, partial, off, cursor);
    scatter_kernel     <<<1024, 256, 0, stream>>>(ei, cursor, sorted2);
    agg_kernel         <<<2048, 256, 0, stream>>>(x, ea, off, sorted2, pre, aggEA);
    mlp1_kernel        <<<196, 256, 0, stream>>>(pre, aggEA, deg, We, be, W1, b1, h);
    bn_stats_kernel    <<<512, 256, 0, stream>>>(h, sums, sumsq);
    mlp2_kernel        <<<196, 256, 0, stream>>>(h, W2, b2, sums, sumsq,
                                                 gamma, beta, (float*)d_out);
}